// Round 3
// baseline (474.716 us; speedup 1.0000x reference)
//
#include <hip/hip_runtime.h>
#include <hip/hip_cooperative_groups.h>

namespace cg = cooperative_groups;

#define NB 4
#define LB 512
#define DB 1024
#define PB 768
#define NBINS 64
#define LEN_KEEP 128          // int(512 * (1 - 0.75))
#define EPSL 1e-19f

#if defined(__has_builtin)
#if __has_builtin(__builtin_amdgcn_exp2f)
#define HAVE_EXP2 1
#endif
#endif

__device__ __forceinline__ float fast_exp2(float x) {
#ifdef HAVE_EXP2
    return __builtin_amdgcn_exp2f(x);   // raw v_exp_f32
#else
    return __expf(x * 0.69314718055994530942f);
#endif
}

// One cooperative kernel, 512 blocks x 256 threads (2 blocks/CU co-resident).
// Phases separated by grid.sync():
//   P1: min/max partials over img (blocks 0..255, float4 loads)
//   P2: final min/max reduce (block 0)
//   P3: KDE entropy, 4 tokens/block, LDS-free inner loop (exp2, per-lane bin)
//   P4: stable rank-by-counting (blocks 0..7) -> mask, ids_restore, ids_keep
//   P5: gather kept x rows (block b -> output row b)
__global__ __launch_bounds__(256, 2) void fused_kernel(
    const float* __restrict__ x, const float* __restrict__ img,
    float* __restrict__ out_x, float* __restrict__ out_mask,
    float* __restrict__ out_rest, float* __restrict__ ws)
{
    cg::grid_group grid = cg::this_grid();
    __shared__ float sh[512];

    float* pmin = ws;                    // 256
    float* pmax = ws + 256;              // 256
    float* mm   = ws + 512;              // 2
    float* ent  = ws + 514;              // 2048
    int*   ids  = (int*)(ws + 514 + NB * LB);   // 512 ints

    int b = blockIdx.x, tid = threadIdx.x;

    // ---------------- P1: min/max partials (blocks 0..255) ----------------
    if (b < 256) {
        const float4* v = (const float4*)img;   // 393216 float4
        int base = b * 256 + tid;
        float mn = 1e30f, mx = -1e30f;
#pragma unroll
        for (int k = 0; k < 6; ++k) {
            float4 t4 = v[base + k * 65536];
            mn = fminf(mn, fminf(fminf(t4.x, t4.y), fminf(t4.z, t4.w)));
            mx = fmaxf(mx, fmaxf(fmaxf(t4.x, t4.y), fmaxf(t4.z, t4.w)));
        }
        sh[tid] = mn; sh[256 + tid] = mx;
        __syncthreads();
        for (int s = 128; s > 0; s >>= 1) {
            if (tid < s) {
                sh[tid]       = fminf(sh[tid], sh[tid + s]);
                sh[256 + tid] = fmaxf(sh[256 + tid], sh[256 + tid + s]);
            }
            __syncthreads();
        }
        if (tid == 0) { pmin[b] = sh[0]; pmax[b] = sh[256]; }
    }
    __threadfence();
    grid.sync();

    // ---------------- P2: final min/max reduce (block 0) ----------------
    if (b == 0) {
        sh[tid] = pmin[tid]; sh[256 + tid] = pmax[tid];
        __syncthreads();
        for (int s = 128; s > 0; s >>= 1) {
            if (tid < s) {
                sh[tid]       = fminf(sh[tid], sh[tid + s]);
                sh[256 + tid] = fmaxf(sh[256 + tid], sh[256 + tid + s]);
            }
            __syncthreads();
        }
        if (tid == 0) { mm[0] = sh[0]; mm[1] = sh[256]; }
    }
    __threadfence();
    grid.sync();

    // ---------------- P3: entropy, 4 tokens per block ----------------
    {
        int lane = tid & 63;     // bin
        int c = tid >> 6;        // value chunk (wave id)
        float vmin = mm[0], vmax = mm[1];
        float rng = vmax - vmin;
        float inv = 1.0f / rng;
        float negK = -7213.4755859375f * inv * inv;  // -(5000*log2 e)*inv^2
        float mb = vmin + (float)lane * (1.0f / 63.0f) * rng;

        for (int u = 0; u < 4; ++u) {
            int t = b * 4 + u;   // token 0..2047
            const float4* row = (const float4*)(img + (size_t)t * PB + c * (PB / 4));
            float a0 = 0.f, a1 = 0.f, a2 = 0.f, a3 = 0.f;
#pragma unroll 4
            for (int i = 0; i < PB / 16; ++i) {   // 48 uniform float4 loads
                float4 v = row[i];
                float d0 = v.x - mb, d1 = v.y - mb, d2 = v.z - mb, d3 = v.w - mb;
                a0 += fast_exp2(d0 * d0 * negK);
                a1 += fast_exp2(d1 * d1 * negK);
                a2 += fast_exp2(d2 * d2 * negK);
                a3 += fast_exp2(d3 * d3 * negK);
            }
            float acc = (a0 + a1) + (a2 + a3);
            __syncthreads();                 // sh reuse barrier
            sh[c * NBINS + lane] = acc;
            __syncthreads();
            if (tid < 64) {                  // one wavefront finishes token t
                float pdf = (sh[lane] + sh[64 + lane] + sh[128 + lane] + sh[192 + lane])
                            * (1.0f / (float)PB);
                float s = pdf;
                for (int m = 1; m < 64; m <<= 1) s += __shfl_xor(s, m, 64);
                float p = pdf / (s + EPSL) + EPSL;
                float term = p * __logf(p);
                for (int m = 1; m < 64; m <<= 1) term += __shfl_xor(term, m, 64);
                if (tid == 0) ent[t] = -term;
            }
        }
    }
    __threadfence();
    grid.sync();

    // ---------------- P4: stable rank-by-counting (blocks 0..7) ----------------
    if (b < 8) {
        int e = b * 256 + tid;              // 0..2047
        int n = e >> 9;                     // row
        int i = e & 511;                    // element
        const float* row = ent + n * LB;
        unsigned long long ci =
            ((unsigned long long)__float_as_uint(row[i]) << 32) | (unsigned int)i;
        int r = 0;
#pragma unroll 8
        for (int j = 0; j < LB; ++j) {      // row[j] uniform -> scalar load
            unsigned long long cj =
                ((unsigned long long)__float_as_uint(row[j]) << 32) | (unsigned int)j;
            r += (cj < ci) ? 1 : 0;
        }
        out_rest[e] = (float)r;
        out_mask[e] = (r < LEN_KEEP) ? 0.0f : 1.0f;
        if (r < LEN_KEEP) ids[n * LEN_KEEP + r] = i;
    }
    __threadfence();
    grid.sync();

    // ---------------- P5: gather (block b -> output row b, b < 512) ----------------
    {
        int n = b >> 7;           // 0..3
        int i = b & 127;          // 0..127
        int row = ids[n * LEN_KEEP + i];
        const float4* src = (const float4*)(x + ((size_t)(n * LB + row)) * DB);
        float4* dst = (float4*)(out_x + ((size_t)b) * DB);
        dst[tid] = src[tid];
    }
}

extern "C" void kernel_launch(void* const* d_in, const int* in_sizes, int n_in,
                              void* d_out, int out_size, void* d_ws, size_t ws_size,
                              hipStream_t stream) {
    const float* x   = (const float*)d_in[0];   // (4,512,1024)
    const float* img = (const float*)d_in[1];   // (4,512,768)

    float* out      = (float*)d_out;
    float* out_x    = out;                               // 4*128*1024
    float* out_mask = out + (size_t)NB * LEN_KEEP * DB;  // 4*512
    float* out_rest = out_mask + NB * LB;                // 4*512
    float* ws       = (float*)d_ws;

    void* args[] = { (void*)&x, (void*)&img, (void*)&out_x,
                     (void*)&out_mask, (void*)&out_rest, (void*)&ws };
    hipLaunchCooperativeKernel((const void*)fused_kernel,
                               dim3(512), dim3(256), args, 0, stream);
}

// Round 4
// 98.677 us; speedup vs baseline: 4.8108x; 4.8108x over previous
//
#include <hip/hip_runtime.h>

#define NB 4
#define LB 512
#define DB 1024
#define PB 768
#define NBINS 64
#define LEN_KEEP 128          // int(512 * (1 - 0.75))
#define EPSL 1e-19f

#if defined(__has_builtin)
#if __has_builtin(__builtin_amdgcn_exp2f)
#define HAVE_EXP2 1
#endif
#endif

__device__ __forceinline__ float fast_exp2(float x) {
#ifdef HAVE_EXP2
    return __builtin_amdgcn_exp2f(x);   // raw v_exp_f32
#else
    return __expf(x * 0.69314718055994530942f);
#endif
}

// ---------------------------------------------------------------------------
// K1: min/max partials over img, 256 blocks x 256 threads, float4 loads.
// ---------------------------------------------------------------------------
__global__ void minmax_partial(const float4* __restrict__ v,
                               float* __restrict__ bmin, float* __restrict__ bmax) {
    __shared__ float smin[256], smax[256];
    int tid = threadIdx.x;
    int base = blockIdx.x * 256 + tid;
    float mn = 1e30f, mx = -1e30f;
#pragma unroll
    for (int k = 0; k < 6; ++k) {
        float4 t4 = v[base + k * 65536];
        mn = fminf(mn, fminf(fminf(t4.x, t4.y), fminf(t4.z, t4.w)));
        mx = fmaxf(mx, fmaxf(fmaxf(t4.x, t4.y), fmaxf(t4.z, t4.w)));
    }
    smin[tid] = mn; smax[tid] = mx;
    __syncthreads();
    for (int s = 128; s > 0; s >>= 1) {
        if (tid < s) {
            smin[tid] = fminf(smin[tid], smin[tid + s]);
            smax[tid] = fmaxf(smax[tid], smax[tid + s]);
        }
        __syncthreads();
    }
    if (tid == 0) { bmin[blockIdx.x] = smin[0]; bmax[blockIdx.x] = smax[0]; }
}

// ---------------------------------------------------------------------------
// K2: KDE entropy, one block per token. Prologue: reduce the 256 min/max
// partials in-block (kills the minmax_final dispatch). Main loop LDS-free:
// exp(-5000*(nv-bv)^2) = 2^(-K*(v-m_b)^2), K = 5000*log2(e)*inv^2,
// m_b = vmin + bv*rng held per-lane (lane = bin).
// ---------------------------------------------------------------------------
__global__ void entropy_kernel(const float* __restrict__ img,
                               const float* __restrict__ bmin,
                               const float* __restrict__ bmax,
                               float* __restrict__ ent) {
    __shared__ float sh[512];
    int t = blockIdx.x;          // token 0..2047
    int tid = threadIdx.x;

    // reduce 256 partials -> vmin/vmax
    sh[tid] = bmin[tid]; sh[256 + tid] = bmax[tid];
    __syncthreads();
    for (int s = 128; s > 0; s >>= 1) {
        if (tid < s) {
            sh[tid]       = fminf(sh[tid], sh[tid + s]);
            sh[256 + tid] = fmaxf(sh[256 + tid], sh[256 + tid + s]);
        }
        __syncthreads();
    }
    float vmin = sh[0], vmax = sh[256];

    int lane = tid & 63;         // bin
    int c = tid >> 6;            // value chunk (wave id)
    float rng = vmax - vmin;
    float inv = 1.0f / rng;
    float negK = -7213.4755859375f * inv * inv;   // -(5000*log2 e)*inv^2
    float mb = vmin + (float)lane * (1.0f / 63.0f) * rng;

    const float4* row = (const float4*)(img + (size_t)t * PB + c * (PB / 4));
    float a0 = 0.f, a1 = 0.f, a2 = 0.f, a3 = 0.f;
#pragma unroll 4
    for (int i = 0; i < PB / 16; ++i) {   // 48 wave-uniform float4 loads
        float4 v = row[i];
        float d0 = v.x - mb, d1 = v.y - mb, d2 = v.z - mb, d3 = v.w - mb;
        a0 += fast_exp2(d0 * d0 * negK);
        a1 += fast_exp2(d1 * d1 * negK);
        a2 += fast_exp2(d2 * d2 * negK);
        a3 += fast_exp2(d3 * d3 * negK);
    }
    float acc = (a0 + a1) + (a2 + a3);

    __syncthreads();             // sh reuse
    sh[c * NBINS + lane] = acc;
    __syncthreads();
    if (tid < 64) {              // one wavefront finishes
        float pdf = (sh[lane] + sh[64 + lane] + sh[128 + lane] + sh[192 + lane])
                    * (1.0f / (float)PB);
        float s = pdf;
        for (int m = 1; m < 64; m <<= 1) s += __shfl_xor(s, m, 64);
        float p = pdf / (s + EPSL) + EPSL;
        float term = p * __logf(p);
        for (int m = 1; m < 64; m <<= 1) term += __shfl_xor(term, m, 64);
        if (tid == 0) ent[t] = -term;
    }
}

// ---------------------------------------------------------------------------
// K3: fused rank + gather. 512 blocks (one per output row), 256 threads.
// Each block ranks its entire entropy row (stable u64 composite, exact
// jnp.argsort semantics), blocks with i==0 write mask/ids_restore, then every
// block gathers the x row whose rank equals its output slot.
// ---------------------------------------------------------------------------
__global__ void rank_gather_kernel(const float* __restrict__ x,
                                   const float* __restrict__ ent,
                                   float* __restrict__ out_x,
                                   float* __restrict__ out_mask,
                                   float* __restrict__ out_rest) {
    __shared__ float sh[512];
    __shared__ int skeep;
    int b = blockIdx.x, tid = threadIdx.x;
    int n = b >> 7;              // row 0..3
    int i = b & 127;             // output slot 0..127

    sh[tid]       = ent[n * LB + tid];
    sh[256 + tid] = ent[n * LB + 256 + tid];
    __syncthreads();

    unsigned long long c0 =
        ((unsigned long long)__float_as_uint(sh[tid]) << 32) | (unsigned int)tid;
    unsigned long long c1 =
        ((unsigned long long)__float_as_uint(sh[256 + tid]) << 32) | (unsigned int)(256 + tid);
    int r0 = 0, r1 = 0;
#pragma unroll 8
    for (int j = 0; j < LB; ++j) {   // LDS broadcast reads
        unsigned long long cj =
            ((unsigned long long)__float_as_uint(sh[j]) << 32) | (unsigned int)j;
        r0 += (cj < c0) ? 1 : 0;
        r1 += (cj < c1) ? 1 : 0;
    }
    if (r0 == i) skeep = tid;        // exactly one thread hits per block
    if (r1 == i) skeep = 256 + tid;
    if (i == 0) {                    // 4 blocks write the row-wide outputs
        out_rest[n * LB + tid]        = (float)r0;
        out_rest[n * LB + 256 + tid]  = (float)r1;
        out_mask[n * LB + tid]        = (r0 < LEN_KEEP) ? 0.0f : 1.0f;
        out_mask[n * LB + 256 + tid]  = (r1 < LEN_KEEP) ? 0.0f : 1.0f;
    }
    __syncthreads();

    int row = skeep;
    const float4* src = (const float4*)(x + ((size_t)(n * LB + row)) * DB);
    float4* dst = (float4*)(out_x + ((size_t)b) * DB);
    dst[tid] = src[tid];
}

extern "C" void kernel_launch(void* const* d_in, const int* in_sizes, int n_in,
                              void* d_out, int out_size, void* d_ws, size_t ws_size,
                              hipStream_t stream) {
    const float* x   = (const float*)d_in[0];   // (4,512,1024)
    const float* img = (const float*)d_in[1];   // (4,512,768)

    float* out      = (float*)d_out;
    float* out_x    = out;                               // 4*128*1024
    float* out_mask = out + (size_t)NB * LEN_KEEP * DB;  // 4*512
    float* out_rest = out_mask + NB * LB;                // 4*512

    float* ws   = (float*)d_ws;
    float* bmin = ws;            // 256
    float* bmax = ws + 256;      // 256
    float* ent  = ws + 512;      // 2048

    minmax_partial<<<256, 256, 0, stream>>>((const float4*)img, bmin, bmax);
    entropy_kernel<<<NB * LB, 256, 0, stream>>>(img, bmin, bmax, ent);
    rank_gather_kernel<<<dim3(NB * LEN_KEEP), 256, 0, stream>>>(x, ent, out_x, out_mask, out_rest);
}

// Round 5
// 87.777 us; speedup vs baseline: 5.4082x; 1.1242x over previous
//
#include <hip/hip_runtime.h>

#define NB 4
#define LB 512
#define DB 1024
#define PB 768
#define NBINS 64
#define LEN_KEEP 128          // int(512 * (1 - 0.75))
#define EPSL 1e-19f
#define WIN 10                // bins beyond +-10 spacings underflow to exact 0.0f

#if defined(__has_builtin)
#if __has_builtin(__builtin_amdgcn_exp2f)
#define HAVE_EXP2 1
#endif
#endif

__device__ __forceinline__ float fast_exp2(float x) {
#ifdef HAVE_EXP2
    return __builtin_amdgcn_exp2f(x);   // raw v_exp_f32
#else
    return __expf(x * 0.69314718055994530942f);
#endif
}

// ---------------------------------------------------------------------------
// K1: min/max partials over img, 256 blocks x 256 threads, float4 loads.
// ---------------------------------------------------------------------------
__global__ void minmax_partial(const float4* __restrict__ v,
                               float* __restrict__ bmin, float* __restrict__ bmax) {
    __shared__ float smin[256], smax[256];
    int tid = threadIdx.x;
    int base = blockIdx.x * 256 + tid;
    float mn = 1e30f, mx = -1e30f;
#pragma unroll
    for (int k = 0; k < 6; ++k) {
        float4 t4 = v[base + k * 65536];
        mn = fminf(mn, fminf(fminf(t4.x, t4.y), fminf(t4.z, t4.w)));
        mx = fmaxf(mx, fmaxf(fmaxf(t4.x, t4.y), fmaxf(t4.z, t4.w)));
    }
    smin[tid] = mn; smax[tid] = mx;
    __syncthreads();
    for (int s = 128; s > 0; s >>= 1) {
        if (tid < s) {
            smin[tid] = fminf(smin[tid], smin[tid + s]);
            smax[tid] = fmaxf(smax[tid], smax[tid + s]);
        }
        __syncthreads();
    }
    if (tid == 0) { bmin[blockIdx.x] = smin[0]; bmax[blockIdx.x] = smax[0]; }
}

// ---------------------------------------------------------------------------
// K2: windowed KDE entropy, one block per token.
//   prologue: reduce 256 min/max partials in-block.
//   counting-sort the 768 normalized values into 64 LDS buckets, then each
//   lane (= bin b) sums exp2(-7213.476*d^2) only over buckets [b-10, b+10]
//   (terms outside underflow to exactly 0.0f in f32 -> numerically exact).
// ---------------------------------------------------------------------------
__global__ void entropy_kernel(const float* __restrict__ img,
                               const float* __restrict__ bmin,
                               const float* __restrict__ bmax,
                               float* __restrict__ ent) {
    __shared__ float sh[512];        // minmax reduce, then per-wave bin partials
    __shared__ float snv[PB];        // bucket-sorted normalized values
    __shared__ int   cnt[NBINS];     // bucket counts
    __shared__ int   bs[NBINS + 1];  // bucket start offsets (exclusive scan)
    __shared__ int   pos[NBINS];     // running scatter cursors

    int t = blockIdx.x;              // token 0..2047
    int tid = threadIdx.x;

    // ---- reduce 256 partials -> vmin/vmax ----
    sh[tid] = bmin[tid]; sh[256 + tid] = bmax[tid];
    if (tid < NBINS) cnt[tid] = 0;
    __syncthreads();
    for (int s = 128; s > 0; s >>= 1) {
        if (tid < s) {
            sh[tid]       = fminf(sh[tid], sh[tid + s]);
            sh[256 + tid] = fmaxf(sh[256 + tid], sh[256 + tid + s]);
        }
        __syncthreads();
    }
    float vmin = sh[0], vmax = sh[256];
    float inv = 1.0f / (vmax - vmin);

    // ---- load my 3 values, normalize, count buckets ----
    const float* row = img + (size_t)t * PB;
    float nv0 = (row[tid]       - vmin) * inv;
    float nv1 = (row[tid + 256] - vmin) * inv;
    float nv2 = (row[tid + 512] - vmin) * inv;
    int m0 = min(63, max(0, __float2int_rn(nv0 * 63.0f)));
    int m1 = min(63, max(0, __float2int_rn(nv1 * 63.0f)));
    int m2 = min(63, max(0, __float2int_rn(nv2 * 63.0f)));
    atomicAdd(&cnt[m0], 1);
    atomicAdd(&cnt[m1], 1);
    atomicAdd(&cnt[m2], 1);
    __syncthreads();

    // ---- exclusive scan of bucket counts (first wave) ----
    if (tid < 64) {
        int c = cnt[tid];
        int incl = c;
        for (int off = 1; off < 64; off <<= 1) {
            int up = __shfl_up(incl, off, 64);
            if (tid >= off) incl += up;
        }
        bs[tid + 1] = incl;
        pos[tid] = incl - c;       // exclusive prefix
        if (tid == 0) bs[0] = 0;
    }
    __syncthreads();

    // ---- scatter values into sorted order ----
    snv[atomicAdd(&pos[m0], 1)] = nv0;
    snv[atomicAdd(&pos[m1], 1)] = nv1;
    snv[atomicAdd(&pos[m2], 1)] = nv2;
    __syncthreads();

    // ---- windowed accumulation: lane = bin, wave = stride-4 slice ----
    int lane = tid & 63;
    int w = tid >> 6;
    float bv = (float)lane * (1.0f / 63.0f);
    int lo = bs[max(0, lane - WIN)];
    int hi = bs[min(NBINS, lane + WIN + 1)];
    const float negC = -7213.4755859375f;   // -(5000 * log2 e)
    float acc = 0.0f;
    for (int j = lo + w; j < hi; j += 4) {
        float d = snv[j] - bv;
        acc += fast_exp2(d * d * negC);
    }
    sh[w * NBINS + lane] = acc;
    __syncthreads();

    // ---- finish: pdf normalize + entropy (one wavefront) ----
    if (tid < 64) {
        float pdf = (sh[lane] + sh[64 + lane] + sh[128 + lane] + sh[192 + lane])
                    * (1.0f / (float)PB);
        float s = pdf;
        for (int m = 1; m < 64; m <<= 1) s += __shfl_xor(s, m, 64);
        float p = pdf / (s + EPSL) + EPSL;
        float term = p * __logf(p);
        for (int m = 1; m < 64; m <<= 1) term += __shfl_xor(term, m, 64);
        if (tid == 0) ent[t] = -term;
    }
}

// ---------------------------------------------------------------------------
// K3: stable rank-by-counting, 8 blocks x 256 threads, one element/thread.
//     Row staged in LDS; u64 (key,idx) composite = exact jnp stable argsort.
// ---------------------------------------------------------------------------
__global__ void rank_kernel(const float* __restrict__ ent,
                            int* __restrict__ ids_keep,
                            float* __restrict__ out_mask,
                            float* __restrict__ out_restore) {
    __shared__ float sh[LB];
    int e = blockIdx.x * 256 + threadIdx.x;   // 0..2047
    int n = e >> 9;                           // row (uniform per block)
    int i = e & 511;                          // element in row
    int tid = threadIdx.x;
    sh[tid]       = ent[n * LB + tid];
    sh[256 + tid] = ent[n * LB + 256 + tid];
    __syncthreads();

    unsigned long long ci =
        ((unsigned long long)__float_as_uint(sh[i & 255 | (i & 256)]) << 32) | (unsigned int)i;
    // (i maps directly: sh holds the full row; index i)
    ci = ((unsigned long long)__float_as_uint(sh[i]) << 32) | (unsigned int)i;
    int r = 0;
#pragma unroll 8
    for (int j = 0; j < LB; ++j) {            // LDS broadcast reads
        unsigned long long cj =
            ((unsigned long long)__float_as_uint(sh[j]) << 32) | (unsigned int)j;
        r += (cj < ci) ? 1 : 0;
    }
    out_restore[e] = (float)r;
    out_mask[e] = (r < LEN_KEEP) ? 0.0f : 1.0f;
    if (r < LEN_KEEP) ids_keep[n * LEN_KEEP + r] = i;
}

// ---------------------------------------------------------------------------
// K4: gather kept rows of x: block (i, n), 256 threads x float4 = 1024 floats
// ---------------------------------------------------------------------------
__global__ void gather_kernel(const float* __restrict__ x,
                              const int* __restrict__ ids_keep,
                              float* __restrict__ out) {
    int i = blockIdx.x;    // 0..127
    int n = blockIdx.y;    // 0..3
    int row = ids_keep[n * LEN_KEEP + i];
    const float4* src = (const float4*)(x + ((size_t)(n * LB + row)) * DB);
    float4* dst = (float4*)(out + ((size_t)(n * LEN_KEEP + i)) * DB);
    dst[threadIdx.x] = src[threadIdx.x];
}

extern "C" void kernel_launch(void* const* d_in, const int* in_sizes, int n_in,
                              void* d_out, int out_size, void* d_ws, size_t ws_size,
                              hipStream_t stream) {
    const float* x   = (const float*)d_in[0];   // (4,512,1024)
    const float* img = (const float*)d_in[1];   // (4,512,768)

    float* out      = (float*)d_out;
    float* out_x    = out;                               // 4*128*1024
    float* out_mask = out + (size_t)NB * LEN_KEEP * DB;  // 4*512
    float* out_rest = out_mask + NB * LB;                // 4*512

    float* ws   = (float*)d_ws;
    float* bmin = ws;            // 256
    float* bmax = ws + 256;      // 256
    float* ent  = ws + 512;      // 2048
    int*   ids  = (int*)(ws + 512 + NB * LB);  // 512 ints

    minmax_partial<<<256, 256, 0, stream>>>((const float4*)img, bmin, bmax);
    entropy_kernel<<<NB * LB, 256, 0, stream>>>(img, bmin, bmax, ent);
    rank_kernel<<<8, 256, 0, stream>>>(ent, ids, out_mask, out_rest);
    gather_kernel<<<dim3(LEN_KEEP, NB), 256, 0, stream>>>(x, ids, out_x);
}